// Round 3
// baseline (8633.306 us; speedup 1.0000x reference)
//
#include <hip/hip_runtime.h>
#include <hip/hip_fp16.h>

// Problem dims
constexpr int kT = 512, kB = 32, kD = 512, kH = 256, kA1 = 16, kA2 = 128;
constexpr int kG = 16;            // LSTM workgroups (hidden-split)
constexpr int kUPW = kH / kG;     // 16 hidden units per WG

typedef _Float16 f16x8 __attribute__((ext_vector_type(8)));
typedef float f32x4 __attribute__((ext_vector_type(4)));
typedef unsigned long long u64;

__device__ __forceinline__ float fast_tanh(float x) {
    float e = __expf(2.0f * x);
    return 1.0f - 2.0f / (e + 1.0f);
}
__device__ __forceinline__ float fast_sig(float x) {
    return 1.0f / (1.0f + __expf(-x));
}
__device__ __forceinline__ unsigned int f16bits(float x) {
    union { _Float16 f; unsigned short u; } c;
    c.f = (_Float16)x;
    return (unsigned int)c.u;
}
__device__ __forceinline__ f16x8 cvt8(const float* p) {
    f16x8 v;
#pragma unroll
    for (int i = 0; i < 8; ++i) v[i] = (_Float16)p[i];
    return v;
}

// ---------------- Kernel 1: attention over feature axis D -> seq (T,B) -------
__global__ __launch_bounds__(256) void att1_kernel(
    const float* __restrict__ x, const float* __restrict__ W1,
    const float* __restrict__ b1, const float* __restrict__ u1,
    float* __restrict__ seq) {
    int blk = blockIdx.x;                 // t*32 + b
    int tid = threadIdx.x;
    const float* xp = x + (size_t)blk * kD;
    float x0 = xp[tid], x1 = xp[tid + 256];
    float s0 = 0.f, s1 = 0.f;
#pragma unroll
    for (int a = 0; a < kA1; ++a) {
        float w = W1[a], bb = b1[a], uu = u1[a];
        s0 += fast_tanh(fmaf(x0, w, bb)) * uu;
        s1 += fast_tanh(fmaf(x1, w, bb)) * uu;
    }
    float e0 = __expf(s0), e1 = __expf(s1);
    float se = e0 + e1;
    float sxe = fmaf(x0, e0, x1 * e1);
#pragma unroll
    for (int m = 32; m; m >>= 1) {
        se  += __shfl_xor(se,  m, 64);
        sxe += __shfl_xor(sxe, m, 64);
    }
    __shared__ float r_se[4], r_sxe[4];
    int wave = tid >> 6, lane = tid & 63;
    if (lane == 0) { r_se[wave] = se; r_sxe[wave] = sxe; }
    __syncthreads();
    if (tid == 0) {
        float S = r_se[0] + r_se[1] + r_se[2] + r_se[3];
        float X = r_sxe[0] + r_sxe[1] + r_sxe[2] + r_sxe[3];
        seq[blk] = X / S;
    }
}

// ---------------- Kernel 2: hidden-split MFMA LSTM ---------------------------
// 16 WGs x 256 threads. WG g owns hidden units [16g, 16g+16) -> 64 gate rows
// packed unit-major. Wave w computes M-tile w (units 4w..4w+3) for all 32
// batches (2 N-tiles). W_hh slice resident in VGPRs as fp16 MFMA A-fragments.
// Cross-wave h exchange: u64 words {tag(hi32) | 2xf16 data(lo32)}, RELAXED
// agent-scope atomics only (no acquire/release -> no buffer_inv L2 nukes).
// Double-buffered by tag parity; tags strictly increase, poison != any tag.
__global__ __launch_bounds__(256, 1) void lstm_kernel(
    const float* __restrict__ seq, const float* __restrict__ W_hh,
    const float* __restrict__ W_ih, const float* __restrict__ b_ih,
    const float* __restrict__ b_hh, const float* __restrict__ h0,
    const float* __restrict__ c0, u64* __restrict__ hglob,
    float* __restrict__ hs) {
    int g   = blockIdx.x;
    int tid = threadIdx.x;
    int w   = tid >> 6;          // wave / M-tile 0..3
    int l   = tid & 63;
    int q   = l >> 4;            // lane quad 0..3
    int col = l & 15;            // batch col (N) / A row (M)

    __shared__ float seq_l[kT * kB];   // 64 KB
    for (int i = tid; i < (kT * kB) / 4; i += 256)
        ((float4*)seq_l)[i] = ((const float4*)seq)[i];

    // ---- A fragments (weights, resident) ----
    int mrow  = col;
    int unitA = 4 * w + (mrow >> 2);
    int gateA = mrow & 3;
    int rA    = gateA * kH + (kUPW * g + unitA);   // original W_hh row
    f16x8 a_frag[8];
#pragma unroll
    for (int kt = 0; kt < 8; ++kt)
        a_frag[kt] = cvt8(W_hh + (size_t)rA * kH + 32 * kt + q * 8);

    // ---- per-lane epilogue params: unit jg = 16g + 4w + q ----
    int jg = kUPW * g + 4 * w + q;
    float wih[4], bias[4];
#pragma unroll
    for (int r = 0; r < 4; ++r) {
        wih[r]  = W_ih[r * kH + jg];
        bias[r] = b_ih[r * kH + jg] + b_hh[r * kH + jg];
    }
    float cA = c0[col * kH + jg];
    float cB = c0[(col + 16) * kH + jg];

    // ---- initial B fragments from h0 (B,H) fp32 ----
    f16x8 b_frag[2][8];
#pragma unroll
    for (int nt = 0; nt < 2; ++nt) {
        int n = 16 * nt + col;
#pragma unroll
        for (int kt = 0; kt < 8; ++kt)
            b_frag[nt][kt] = cvt8(h0 + n * kH + 32 * kt + q * 8);
    }
    int kp = 8 * g + 2 * w + (q >> 1);     // u32 k-pair index this lane publishes
    __syncthreads();                        // seq_l ready

    for (int t = 0; t < kT; ++t) {
        f32x4 acc0 = {0.f, 0.f, 0.f, 0.f};
        f32x4 acc1 = {0.f, 0.f, 0.f, 0.f};
#pragma unroll
        for (int kt = 0; kt < 8; ++kt) {
            acc0 = __builtin_amdgcn_mfma_f32_16x16x32_f16(a_frag[kt], b_frag[0][kt], acc0, 0, 0, 0);
            acc1 = __builtin_amdgcn_mfma_f32_16x16x32_f16(a_frag[kt], b_frag[1][kt], acc1, 0, 0, 0);
        }
        // C layout: col = lane&15 (batch), row = q*4 + reg -> unit 4w+q, gate=reg
        float xA = seq_l[t * kB + col];
        float xB = seq_l[t * kB + col + 16];
        float iA = fast_sig (acc0[0] + wih[0] * xA + bias[0]);
        float fA = fast_sig (acc0[1] + wih[1] * xA + bias[1]);
        float gA = fast_tanh(acc0[2] + wih[2] * xA + bias[2]);
        float oA = fast_sig (acc0[3] + wih[3] * xA + bias[3]);
        cA = fmaf(fA, cA, iA * gA);
        float hA = oA * fast_tanh(cA);
        float iB = fast_sig (acc1[0] + wih[0] * xB + bias[0]);
        float fB = fast_sig (acc1[1] + wih[1] * xB + bias[1]);
        float gB = fast_tanh(acc1[2] + wih[2] * xB + bias[2]);
        float oB = fast_sig (acc1[3] + wih[3] * xB + bias[3]);
        cB = fmaf(fB, cB, iB * gB);
        float hB = oB * fast_tanh(cB);

        // hs output (fp32, [t][b][j])
        hs[((size_t)t * kB + col) * kH + jg]      = hA;
        hs[((size_t)t * kB + col + 16) * kH + jg] = hB;

        if (t == kT - 1) break;

        unsigned int want = (unsigned int)(t + 1);
        u64* hb = hglob + ((t + 1) & 1) * (kB * 128);   // [n][j], j = k/2, 0..127

        // ---- publish h_{t+1}: tagged u64, relaxed agent atomics ----
        float pA = __shfl_xor(hA, 16, 64);   // partner unit jg^1 (q^1)
        float pB = __shfl_xor(hB, 16, 64);
        if ((q & 1) == 0) {
            u64 uA = ((u64)want << 32) | (u64)(f16bits(hA) | (f16bits(pA) << 16));
            u64 uB = ((u64)want << 32) | (u64)(f16bits(hB) | (f16bits(pB) << 16));
            __hip_atomic_store(&hb[col * 128 + kp], uA,
                               __ATOMIC_RELAXED, __HIP_MEMORY_SCOPE_AGENT);
            __hip_atomic_store(&hb[(col + 16) * 128 + kp], uB,
                               __ATOMIC_RELAXED, __HIP_MEMORY_SCOPE_AGENT);
        }

        // ---- gather h_{t+1}: poll tagged words, data itself is the sync ----
        u64 vv[2][8][4];
        bool ok;
        do {
            ok = true;
#pragma unroll
            for (int nt = 0; nt < 2; ++nt) {
                int nb = (16 * nt + col) * 128;
#pragma unroll
                for (int kt = 0; kt < 8; ++kt)
#pragma unroll
                    for (int i = 0; i < 4; ++i) {
                        u64 v = __hip_atomic_load(&hb[nb + 16 * kt + 4 * q + i],
                                                  __ATOMIC_RELAXED, __HIP_MEMORY_SCOPE_AGENT);
                        vv[nt][kt][i] = v;
                        ok &= ((unsigned int)(v >> 32) == want);
                    }
            }
            if (!ok) __builtin_amdgcn_s_sleep(1);
        } while (!ok);
#pragma unroll
        for (int nt = 0; nt < 2; ++nt)
#pragma unroll
            for (int kt = 0; kt < 8; ++kt) {
                union { unsigned int u[4]; f16x8 v; } tmp;
#pragma unroll
                for (int i = 0; i < 4; ++i) tmp.u[i] = (unsigned int)vv[nt][kt][i];
                b_frag[nt][kt] = tmp.v;
            }
    }
}

// ---------------- Kernel 3a: attention-2 scores e2 (T,B) ---------------------
__global__ __launch_bounds__(128) void att2a_kernel(
    const float* __restrict__ hs, const float* __restrict__ W2,
    const float* __restrict__ b2, const float* __restrict__ u2,
    float* __restrict__ a2w) {
    int b  = blockIdx.x & 31;
    int tc = blockIdx.x >> 5;   // 0..31
    int a  = threadIdx.x;       // 0..127
    __shared__ __align__(16) float hl[16][kH];
    __shared__ float red[16][2];
    int t0 = tc * 16;
    for (int tt = 0; tt < 16; ++tt) {
        const float* hp = hs + ((size_t)(t0 + tt) * kB + b) * kH;
        hl[tt][a]       = hp[a];
        hl[tt][a + 128] = hp[a + 128];
    }
    __syncthreads();
    float dot[16];
#pragma unroll
    for (int tt = 0; tt < 16; ++tt) dot[tt] = 0.f;
    for (int k = 0; k < kH; k += 4) {
        float w0 = W2[(k + 0) * kA2 + a];
        float w1 = W2[(k + 1) * kA2 + a];
        float w2 = W2[(k + 2) * kA2 + a];
        float w3 = W2[(k + 3) * kA2 + a];
#pragma unroll
        for (int tt = 0; tt < 16; ++tt) {
            float4 h4 = *(const float4*)&hl[tt][k];
            dot[tt] = fmaf(h4.x, w0, dot[tt]);
            dot[tt] = fmaf(h4.y, w1, dot[tt]);
            dot[tt] = fmaf(h4.z, w2, dot[tt]);
            dot[tt] = fmaf(h4.w, w3, dot[tt]);
        }
    }
    float bb = b2[a], uu = u2[a];
    int wave = a >> 6, lane = a & 63;
#pragma unroll
    for (int tt = 0; tt < 16; ++tt) {
        float v = fast_tanh(dot[tt] + bb) * uu;
#pragma unroll
        for (int m = 32; m; m >>= 1) v += __shfl_xor(v, m, 64);
        if (lane == 0) red[tt][wave] = v;
    }
    __syncthreads();
    if (a < 16) {
        float s = red[a][0] + red[a][1];
        a2w[(t0 + a) * kB + b] = __expf(s);
    }
}

// ---------------- Kernel 3b: weighted time-pool + linear head ----------------
__global__ __launch_bounds__(256) void att2b_kernel(
    const float* __restrict__ hs, const float* __restrict__ a2w,
    const float* __restrict__ Wl, const float* __restrict__ bl,
    float* __restrict__ out) {
    int b = blockIdx.x;
    int k = threadIdx.x;
    float acc = 0.f, den = 0.f;
    for (int t = 0; t < kT; ++t) {
        float e = a2w[t * kB + b];
        float h = hs[((size_t)t * kB + b) * kH + k];
        acc = fmaf(h, e, acc);
        den += e;
    }
    float v = (acc / den) * Wl[k];
#pragma unroll
    for (int m = 32; m; m >>= 1) v += __shfl_xor(v, m, 64);
    __shared__ float red[4];
    int wave = k >> 6, lane = k & 63;
    if (lane == 0) red[wave] = v;
    __syncthreads();
    if (k == 0) out[b] = red[0] + red[1] + red[2] + red[3] + bl[0];
}

extern "C" void kernel_launch(void* const* d_in, const int* in_sizes, int n_in,
                              void* d_out, int out_size, void* d_ws, size_t ws_size,
                              hipStream_t stream) {
    const float* inputs = (const float*)d_in[0];
    const float* W1   = (const float*)d_in[1];
    const float* b1   = (const float*)d_in[2];
    const float* u1   = (const float*)d_in[3];
    const float* W_ih = (const float*)d_in[4];
    const float* W_hh = (const float*)d_in[5];
    const float* b_ih = (const float*)d_in[6];
    const float* b_hh = (const float*)d_in[7];
    const float* h0   = (const float*)d_in[8];
    const float* c0   = (const float*)d_in[9];
    const float* W2   = (const float*)d_in[10];
    const float* b2   = (const float*)d_in[11];
    const float* u2   = (const float*)d_in[12];
    const float* Wl   = (const float*)d_in[13];
    const float* bl   = (const float*)d_in[14];
    float* out = (float*)d_out;

    char* ws = (char*)d_ws;
    float* seq   = (float*)(ws);                  // 64 KB (T*B fp32)
    float* a2w   = (float*)(ws + (64 << 10));     // 64 KB (T*B fp32)
    u64*   hglob = (u64*)(ws + (128 << 10));      // 64 KB (2 parities x B x 128 u64)
    float* hs    = (float*)(ws + (1 << 20));      // 16 MB (T*B*H fp32)

    att1_kernel <<<kT * kB, 256, 0, stream>>>(inputs, W1, b1, u1, seq);
    lstm_kernel <<<kG, 256, 0, stream>>>(seq, W_hh, W_ih, b_ih, b_hh, h0, c0,
                                         hglob, hs);
    att2a_kernel<<<1024, 128, 0, stream>>>(hs, W2, b2, u2, a2w);
    att2b_kernel<<<kB, 256, 0, stream>>>(hs, a2w, Wl, bl, out);
}

// Round 6
// 2770.618 us; speedup vs baseline: 3.1160x; 3.1160x over previous
//
#include <hip/hip_runtime.h>
#include <hip/hip_fp16.h>

// Problem dims
constexpr int kT = 512, kB = 32, kD = 512, kH = 256, kA1 = 16, kA2 = 128;
constexpr int kG = 8;             // LSTM workgroups (hidden-split), any CUs

typedef _Float16 f16x8 __attribute__((ext_vector_type(8)));
typedef float f32x4 __attribute__((ext_vector_type(4)));
typedef unsigned long long u64;
typedef unsigned int u32;
typedef u32 u32x2 __attribute__((ext_vector_type(2)));
typedef u32 u32x4 __attribute__((ext_vector_type(4)));

__device__ __forceinline__ float fast_tanh(float x) {
    float e = __expf(2.0f * x);
    return 1.0f - 2.0f / (e + 1.0f);
}
__device__ __forceinline__ float fast_sig(float x) {
    return 1.0f / (1.0f + __expf(-x));
}
__device__ __forceinline__ u32 f16bits(float x) {
    union { _Float16 f; unsigned short u; } c;
    c.f = (_Float16)x;
    return (u32)c.u;
}
__device__ __forceinline__ f16x8 cvt8(const float* p) {
    f16x8 v;
#pragma unroll
    for (int i = 0; i < 8; ++i) v[i] = (_Float16)p[i];
    return v;
}
// System-scope (MALL-coherent) ops — same coherence point for store & load.
// These are the asm forms of relaxed system-scope atomics (proven R1-R3),
// hand-written so 16 loads pipeline under ONE s_waitcnt.
__device__ __forceinline__ void store_sys8(void* p, u32 d, u32 tag) {
    u32x2 v; v.x = d; v.y = tag;
    asm volatile("global_store_dwordx2 %0, %1, off sc0 sc1"
                 :: "v"(p), "v"(v) : "memory");
}
__device__ __forceinline__ u32x4 load_sys16(const void* p) {
    u32x4 v;
    asm volatile("global_load_dwordx4 %0, %1, off sc0 sc1"
                 : "=v"(v) : "v"(p) : "memory");
    return v;
}

// ---------------- Kernel 1: attention over feature axis D -> seq (T,B) -------
__global__ __launch_bounds__(256) void att1_kernel(
    const float* __restrict__ x, const float* __restrict__ W1,
    const float* __restrict__ b1, const float* __restrict__ u1,
    float* __restrict__ seq) {
    int blk = blockIdx.x;                 // t*32 + b
    int tid = threadIdx.x;
    const float* xp = x + (size_t)blk * kD;
    float x0 = xp[tid], x1 = xp[tid + 256];
    float s0 = 0.f, s1 = 0.f;
#pragma unroll
    for (int a = 0; a < kA1; ++a) {
        float w = W1[a], bb = b1[a], uu = u1[a];
        s0 += fast_tanh(fmaf(x0, w, bb)) * uu;
        s1 += fast_tanh(fmaf(x1, w, bb)) * uu;
    }
    float e0 = __expf(s0), e1 = __expf(s1);
    float se = e0 + e1;
    float sxe = fmaf(x0, e0, x1 * e1);
#pragma unroll
    for (int m = 32; m; m >>= 1) {
        se  += __shfl_xor(se,  m, 64);
        sxe += __shfl_xor(sxe, m, 64);
    }
    __shared__ float r_se[4], r_sxe[4];
    int wave = tid >> 6, lane = tid & 63;
    if (lane == 0) { r_se[wave] = se; r_sxe[wave] = sxe; }
    __syncthreads();
    if (tid == 0) {
        float S = r_se[0] + r_se[1] + r_se[2] + r_se[3];
        float X = r_sxe[0] + r_sxe[1] + r_sxe[2] + r_sxe[3];
        seq[blk] = X / S;
    }
}

// ---------------- Kernel 2: hidden-split MFMA LSTM, tagged-MALL exchange -----
// 8 WGs x 256 threads. WG g owns hidden units [32g, 32g+32) = 128 gate rows,
// unit-major packing (row = 4*unit_local + gate; PyTorch gate order i,f,g,o).
// Wave w: nt=w>>1 (batch half), mh=w&1 (16-unit half). W_hh slice resident in
// VGPRs as fp16 MFMA A-fragments. Exchange: hbuf[t][b][kp] = u64
// {lo32: 2xf16 h for units 2kp,2kp+1; hi32: tag t+1}. Publish & gather both
// system-scope (sc0 sc1 -> MALL), so one coherence point; the tag travels
// with the data, so no fences, no sentinel, no in-loop barriers.
__global__ __launch_bounds__(256, 1) void lstm_kernel(
    const float* __restrict__ seq, const float* __restrict__ W_hh,
    const float* __restrict__ W_ih, const float* __restrict__ b_ih,
    const float* __restrict__ b_hh, const float* __restrict__ h0,
    const float* __restrict__ c0, u64* __restrict__ hbuf) {
    int g   = blockIdx.x;
    int tid = threadIdx.x;
    int w   = tid >> 6;          // wave 0..3
    int l   = tid & 63;
    int q   = l >> 4;            // lane quad 0..3
    int col = l & 15;
    int nt  = w >> 1;            // batch half
    int mh  = w & 1;             // unit half within WG
    int bcol = nt * 16 + col;    // this lane's batch (N col)

    __shared__ float seq_l[kT * kB];   // 64 KB
    for (int i = tid; i < (kT * kB) / 4; i += 256)
        ((float4*)seq_l)[i] = ((const float4*)seq)[i];

    // ---- A fragments (weights, resident): 4 m-tiles x 8 k-tiles ----
    // tile mt, local row m=col: unit u = 32g+16mh+4mt+(m>>2), gate = m&3
    // A[m][k]: k = 32kt + 8q + i
    f16x8 a_frag[4][8];
#pragma unroll
    for (int mt = 0; mt < 4; ++mt) {
        int u  = 32 * g + 16 * mh + 4 * mt + (col >> 2);
        int rW = (col & 3) * kH + u;
#pragma unroll
        for (int kt = 0; kt < 8; ++kt)
            a_frag[mt][kt] = cvt8(W_hh + (size_t)rW * kH + 32 * kt + 8 * q);
    }

    // ---- epilogue params: lane owns unit u(mt) = 32g+16mh+4mt+q, batch bcol
    float wih[4][4], bias[4][4], c[4];
#pragma unroll
    for (int mt = 0; mt < 4; ++mt) {
        int u = 32 * g + 16 * mh + 4 * mt + q;
#pragma unroll
        for (int r = 0; r < 4; ++r) {
            wih[mt][r]  = W_ih[r * kH + u];
            bias[mt][r] = b_ih[r * kH + u] + b_hh[r * kH + u];
        }
        c[mt] = c0[bcol * kH + u];
    }

    // ---- initial B fragments from h0: B[k][n=bcol], k = 32kt + 8q + i ----
    f16x8 b_frag[8];
#pragma unroll
    for (int kt = 0; kt < 8; ++kt)
        b_frag[kt] = cvt8(h0 + bcol * kH + 32 * kt + 8 * q);

    __syncthreads();   // seq_l ready
    bool dead = false;

    for (int t = 0; t < kT; ++t) {
        f32x4 acc[4] = {{0,0,0,0},{0,0,0,0},{0,0,0,0},{0,0,0,0}};
#pragma unroll
        for (int kt = 0; kt < 8; ++kt) {
            f16x8 bf = b_frag[kt];
#pragma unroll
            for (int mt = 0; mt < 4; ++mt)
                acc[mt] = __builtin_amdgcn_mfma_f32_16x16x32_f16(a_frag[mt][kt], bf, acc[mt], 0, 0, 0);
        }
        // C layout: col = lane&15 (batch), row = 4q + reg -> unit u(mt), gate=reg
        float xv = seq_l[t * kB + bcol];
        float hv[4];
#pragma unroll
        for (int mt = 0; mt < 4; ++mt) {
            float ig = fast_sig (acc[mt][0] + wih[mt][0] * xv + bias[mt][0]);
            float fg = fast_sig (acc[mt][1] + wih[mt][1] * xv + bias[mt][1]);
            float gg = fast_tanh(acc[mt][2] + wih[mt][2] * xv + bias[mt][2]);
            float og = fast_sig (acc[mt][3] + wih[mt][3] * xv + bias[mt][3]);
            c[mt] = fmaf(fg, c[mt], ig * gg);
            hv[mt] = og * fast_tanh(c[mt]);
        }

        u32 want = (u32)(t + 1);
        u64* hstep = hbuf + (size_t)t * (kB * 128);   // [b][kp], kp = unit/2

        // ---- publish: tagged u64 pairs, fire-and-forget system stores ----
#pragma unroll
        for (int mt = 0; mt < 4; ++mt) {
            float pv = __shfl_xor(hv[mt], 16, 64);    // partner unit (q^1)
            if ((q & 1) == 0) {
                int kp = 16 * g + 8 * mh + 2 * mt + (q >> 1);
                store_sys8(&hstep[(size_t)bcol * 128 + kp],
                           f16bits(hv[mt]) | (f16bits(pv) << 16), want);
            }
        }

        if (t == kT - 1) break;
        if (dead) continue;

        // ---- gather: 16 pipelined system loads, tag-checked, retry ----
        const u64* grow = hstep + (size_t)bcol * 128;
        u32x4 r[16];
        bool ok;
        int tries = 0;
        do {
#pragma unroll
            for (int kt = 0; kt < 8; ++kt) {
                r[2 * kt]     = load_sys16(&grow[16 * kt + 4 * q]);
                r[2 * kt + 1] = load_sys16(&grow[16 * kt + 4 * q + 2]);
            }
            asm volatile("s_waitcnt vmcnt(0)" ::: "memory");
            ok = true;
#pragma unroll
            for (int i = 0; i < 16; ++i) ok = ok && (r[i].y == want) && (r[i].w == want);
            if (++tries > (1 << 12)) { dead = true; break; }
        } while (!ok);
        if (dead) continue;

#pragma unroll
        for (int kt = 0; kt < 8; ++kt) {
            union { u32 u[4]; f16x8 v; } tmp;
            tmp.u[0] = r[2 * kt].x;     tmp.u[1] = r[2 * kt].z;
            tmp.u[2] = r[2 * kt + 1].x; tmp.u[3] = r[2 * kt + 1].z;
            b_frag[kt] = tmp.v;
        }
    }
}

// ---------------- Kernel 3a: attention-2 scores from tagged hbuf -------------
// hb is the u32 view: word ((t*32+b)*128 + kp)*2 = packed f16 pair (2kp,2kp+1)
__global__ __launch_bounds__(128) void att2a_kernel(
    const u32* __restrict__ hb, const float* __restrict__ W2,
    const float* __restrict__ b2, const float* __restrict__ u2,
    float* __restrict__ a2w) {
    int b  = blockIdx.x & 31;
    int tc = blockIdx.x >> 5;   // 0..31
    int a  = threadIdx.x;       // 0..127
    __shared__ __align__(16) float hl[16][kH];
    __shared__ float red[16][2];
    int t0 = tc * 16;
    for (int tt = 0; tt < 16; ++tt) {
        size_t base = ((size_t)(t0 + tt) * kB + b) * 256;   // u32 words per row
        union { u32 u; _Float16 h[2]; } cv;
        cv.u = hb[base + 2 * a];
        hl[tt][2 * a]     = (float)cv.h[0];
        hl[tt][2 * a + 1] = (float)cv.h[1];
    }
    __syncthreads();
    float dot[16];
#pragma unroll
    for (int tt = 0; tt < 16; ++tt) dot[tt] = 0.f;
    for (int k = 0; k < kH; k += 4) {
        float w0 = W2[(k + 0) * kA2 + a];
        float w1 = W2[(k + 1) * kA2 + a];
        float w2 = W2[(k + 2) * kA2 + a];
        float w3 = W2[(k + 3) * kA2 + a];
#pragma unroll
        for (int tt = 0; tt < 16; ++tt) {
            float4 h4 = *(const float4*)&hl[tt][k];
            dot[tt] = fmaf(h4.x, w0, dot[tt]);
            dot[tt] = fmaf(h4.y, w1, dot[tt]);
            dot[tt] = fmaf(h4.z, w2, dot[tt]);
            dot[tt] = fmaf(h4.w, w3, dot[tt]);
        }
    }
    float bb = b2[a], uu = u2[a];
    int wave = a >> 6, lane = a & 63;
#pragma unroll
    for (int tt = 0; tt < 16; ++tt) {
        float v = fast_tanh(dot[tt] + bb) * uu;
#pragma unroll
        for (int m = 32; m; m >>= 1) v += __shfl_xor(v, m, 64);
        if (lane == 0) red[tt][wave] = v;
    }
    __syncthreads();
    if (a < 16) {
        float s = red[a][0] + red[a][1];
        a2w[(t0 + a) * kB + b] = __expf(s);
    }
}

// ---------------- Kernel 3b: weighted time-pool + linear head ----------------
__global__ __launch_bounds__(256) void att2b_kernel(
    const u32* __restrict__ hb, const float* __restrict__ a2w,
    const float* __restrict__ Wl, const float* __restrict__ bl,
    float* __restrict__ out) {
    int b = blockIdx.x;
    int k = threadIdx.x;
    float acc = 0.f, den = 0.f;
    for (int t = 0; t < kT; ++t) {
        float e = a2w[t * kB + b];
        union { u32 u; _Float16 h[2]; } cv;
        cv.u = hb[((size_t)t * kB + b) * 256 + (k >> 1) * 2];
        float h = (float)cv.h[k & 1];
        acc = fmaf(h, e, acc);
        den += e;
    }
    float v = (acc / den) * Wl[k];
#pragma unroll
    for (int m = 32; m; m >>= 1) v += __shfl_xor(v, m, 64);
    __shared__ float red[4];
    int wave = k >> 6, lane = k & 63;
    if (lane == 0) red[wave] = v;
    __syncthreads();
    if (k == 0) out[b] = red[0] + red[1] + red[2] + red[3] + bl[0];
}

extern "C" void kernel_launch(void* const* d_in, const int* in_sizes, int n_in,
                              void* d_out, int out_size, void* d_ws, size_t ws_size,
                              hipStream_t stream) {
    const float* inputs = (const float*)d_in[0];
    const float* W1   = (const float*)d_in[1];
    const float* b1   = (const float*)d_in[2];
    const float* u1   = (const float*)d_in[3];
    const float* W_ih = (const float*)d_in[4];
    const float* W_hh = (const float*)d_in[5];
    const float* b_ih = (const float*)d_in[6];
    const float* b_hh = (const float*)d_in[7];
    const float* h0   = (const float*)d_in[8];
    const float* c0   = (const float*)d_in[9];
    const float* W2   = (const float*)d_in[10];
    const float* b2   = (const float*)d_in[11];
    const float* u2   = (const float*)d_in[12];
    const float* Wl   = (const float*)d_in[13];
    const float* bl   = (const float*)d_in[14];
    float* out = (float*)d_out;

    char* ws = (char*)d_ws;
    float* seq  = (float*)(ws);                 // 64 KB (T*B fp32)
    float* a2w  = (float*)(ws + (64 << 10));    // 64 KB (T*B fp32)
    u64*   hbuf = (u64*)(ws + (128 << 10));     // 16 MB (T x B x 128 tagged u64)

    att1_kernel <<<kT * kB, 256, 0, stream>>>(inputs, W1, b1, u1, seq);
    lstm_kernel <<<kG, 256, 0, stream>>>(seq, W_hh, W_ih, b_ih, b_hh, h0, c0, hbuf);
    att2a_kernel<<<1024, 128, 0, stream>>>((const u32*)hbuf, W2, b2, u2, a2w);
    att2b_kernel<<<kB, 256, 0, stream>>>((const u32*)hbuf, a2w, Wl, bl, out);
}